// Round 3
// baseline (244.495 us; speedup 1.0000x reference)
//
#include <hip/hip_runtime.h>

// ForwardTransformLayer: lifting step with circular 8-tap convolutions.
//   even = in[:, ::2], odd = in[:, 1::2]            (row length 8192 -> 4096 each)
//   odd_out[k]  = odd[k]  - sum_j even[(k-j) mod n] * wavelet[j]
//   even_out[k] = even[k] - sum_j odd[(k-j)  mod n] * scaling[j]
//   wavelet[j] = scaling_rec[7-j] * (j odd ? -1 : +1)
// d_out layout: even_out (rows*4096) then odd_out (rows*4096), row-major.
//
// R6 = R5 with the compile fix: __builtin_nontemporal_store requires a
// native clang vector type, not HIP_vector_type<float,4>. Use
// ext_vector_type(4) float (same 16-B layout -> one global_store_dwordx4 nt).
//
// Theory (unchanged): R2/R3/R4 (different traffic, occupancy, pipelining)
// all pinned at ~80 us -> kernel insensitive to bytes/occupancy/issue
// timing. Suspect: L3 write-allocate churn. The harness poison-fill dirties
// 536 MB through L2/L3 right before each iteration; our 134 MB of stores
// then allocate and evict dirty poison (~400 MB L3-side traffic @ ~5 TB/s
// = the observed 80 us), invisible to FETCH_SIZE/VALUBusy. Nontemporal
// stores stream outputs past the caches; input keeps its L3 read hits.

#define COLS       8192
#define HALF       4096
#define PAIRS_PT   8                          // pairs (outputs per array) per thread
#define NTHREADS   256
#define THREADS_PER_ROW (HALF / PAIRS_PT)     // 512 = 8 waves -> waves never straddle rows

typedef float f32x4 __attribute__((ext_vector_type(4)));

__global__ __launch_bounds__(NTHREADS) void fwd_dwt_kernel(
    const float* __restrict__ input,
    const float* __restrict__ scaling,
    const float* __restrict__ scaling_rec,
    float* __restrict__ out,
    int rows)
{
    const int g     = blockIdx.x * NTHREADS + threadIdx.x;
    const int row   = g / THREADS_PER_ROW;
    const int chunk = g % THREADS_PER_ROW;
    const int k0    = chunk * PAIRS_PT;       // first output pair index
    const int lane  = threadIdx.x & 63;

    const float* in_row = input + (size_t)row * COLS;

    // Filters (uniform scalar loads, L1-cached).
    float w[8], sc[8];
#pragma unroll
    for (int j = 0; j < 8; ++j) {
        w[j]  = scaling_rec[7 - j] * ((j & 1) ? -1.0f : 1.0f);
        sc[j] = scaling[j];
    }

    // Payload: this lane's 8 pairs (4 aligned float4, each lane reads only
    // its own 128 B -> wave covers a contiguous 8 KB, no amplification).
    float4 v[4];
    const float4* p_pay = (const float4*)(in_row + 2 * k0);
#pragma unroll
    for (int i = 0; i < 4; ++i) v[i] = p_pay[i];

    float E[8], O[8];
#pragma unroll
    for (int i = 0; i < 4; ++i) {
        E[2 * i]     = v[i].x;  O[2 * i]     = v[i].y;
        E[2 * i + 1] = v[i].z;  O[2 * i + 1] = v[i].w;
    }

    // Full windows EF/OF[i] = pair (k0-7+i), i = 0..14.
    // EF[7..14] = own payload; EF[0..6] = previous chunk's pairs 1..7,
    // fetched from lane-1 via shfl_up (garbage on lane 0, patched below).
    float EF[15], OF[15];
#pragma unroll
    for (int i = 0; i < 8; ++i) { EF[7 + i] = E[i]; OF[7 + i] = O[i]; }
#pragma unroll
    for (int i = 1; i < 8; ++i) {
        EF[i - 1] = __shfl_up(E[i], 1);
        OF[i - 1] = __shfl_up(O[i], 1);
    }

    // Lane 0: previous chunk lives in the previous wave (or row tail for
    // chunk 0 -> circular wrap). Load its 8 pairs (4 float4, 64 B).
    if (lane == 0) {
        const int hb = (k0 - PAIRS_PT) & (HALF - 1);
        const float4* p_halo = (const float4*)(in_row + 2 * hb);
        float4 h[4];
#pragma unroll
        for (int i = 0; i < 4; ++i) h[i] = p_halo[i];
        // prev pair p: float4 h[p/2]; even = .x/.z, odd = .y/.w
#pragma unroll
        for (int p = 1; p < 8; ++p) {
            EF[p - 1] = (p & 1) ? h[p / 2].z : h[p / 2].x;
            OF[p - 1] = (p & 1) ? h[p / 2].w : h[p / 2].y;
        }
    }

    // even_out[k0+q] = E[q] - sum_j OF[7+q-j]*sc[j]
    // odd_out [k0+q] = O[q] - sum_j EF[7+q-j]*w[j]
    float eo[8], oo[8];
#pragma unroll
    for (int q = 0; q < 8; ++q) {
        float a = 0.0f, b = 0.0f;
#pragma unroll
        for (int j = 0; j < 8; ++j) {
            a += OF[7 + q - j] * sc[j];
            b += EF[7 + q - j] * w[j];
        }
        eo[q] = E[q] - a;
        oo[q] = O[q] - b;
    }

    float* oe = out + (size_t)row * HALF + k0;
    float* od = out + (size_t)rows * HALF + (size_t)row * HALF + k0;

    // Nontemporal: stream outputs past L2/L3 (no write-allocate, no dirty
    // poison eviction churn). Coherence is preserved; only caching changes.
    f32x4 e0 = {eo[0], eo[1], eo[2], eo[3]};
    f32x4 e1 = {eo[4], eo[5], eo[6], eo[7]};
    f32x4 o0 = {oo[0], oo[1], oo[2], oo[3]};
    f32x4 o1 = {oo[4], oo[5], oo[6], oo[7]};
    __builtin_nontemporal_store(e0, (f32x4*)oe + 0);
    __builtin_nontemporal_store(e1, (f32x4*)oe + 1);
    __builtin_nontemporal_store(o0, (f32x4*)od + 0);
    __builtin_nontemporal_store(o1, (f32x4*)od + 1);
}

extern "C" void kernel_launch(void* const* d_in, const int* in_sizes, int n_in,
                              void* d_out, int out_size, void* d_ws, size_t ws_size,
                              hipStream_t stream) {
    const float* input       = (const float*)d_in[0];
    const float* scaling     = (const float*)d_in[1];
    const float* scaling_rec = (const float*)d_in[2];
    float*       out         = (float*)d_out;

    const int rows    = in_sizes[0] / COLS;                 // 4096
    const int threads = rows * THREADS_PER_ROW;             // 2,097,152
    fwd_dwt_kernel<<<threads / NTHREADS, NTHREADS, 0, stream>>>(
        input, scaling, scaling_rec, out, rows);
}

// Round 4
// 238.554 us; speedup vs baseline: 1.0249x; 1.0249x over previous
//
#include <hip/hip_runtime.h>

// ForwardTransformLayer: lifting step with circular 8-tap convolutions.
//   even = in[:, ::2], odd = in[:, 1::2]            (row length 8192 -> 4096 each)
//   odd_out[k]  = odd[k]  - sum_j even[(k-j) mod n] * wavelet[j]
//   even_out[k] = even[k] - sum_j odd[(k-j)  mod n] * scaling[j]
//   wavelet[j] = scaling_rec[7-j] * (j odd ? -1 : +1)
// d_out layout: even_out (rows*4096) then odd_out (rows*4096), row-major.
//
// R7 design: ~80 us is invariant under traffic (R2), halo scheme (R3),
// occupancy/pipelining (R4), and store cache policy (R6/NT -- which made
// WRITE_SIZE go UP via partial-line writebacks). The one constant across
// all of them: per-INSTRUCTION address fan-out. Old payload loads touched
// 64 distinct 64-B lines per instruction (16 B/lane at 128-B stride);
// stores half-touched 32 lines (16 B/lane at 32-B stride). The 6.29 TB/s
// measured ceiling is a DENSE float4 copy -- same bytes as us, dense issue.
// Fix: 1 float4 (2 pairs) per thread. Payload load = lane-contiguous 1 KB
// per instruction; outputs = float2 stores, lane-contiguous 512 B per
// instruction. History window via __shfl_up d=1..4 (14 shfl/thread);
// lanes 0..3 patch missing predecessors with exec-masked loads from one
// 64-B line (circular row wrap handled).

#define COLS       8192
#define HALF       4096                       // pairs per row
#define F4_PER_ROW 2048                       // float4s per row (2 pairs each)
#define NTHREADS   256

__global__ __launch_bounds__(NTHREADS) void fwd_dwt_kernel(
    const float* __restrict__ input,
    const float* __restrict__ scaling,
    const float* __restrict__ scaling_rec,
    float* __restrict__ out,
    int rows)
{
    const int t    = blockIdx.x * NTHREADS + threadIdx.x;  // global float4 index
    const int row  = t >> 11;                               // /F4_PER_ROW
    const int tl   = t & (F4_PER_ROW - 1);                  // row-local float4 idx
    const int lane = threadIdx.x & 63;

    const float* in_row = input + (size_t)row * COLS;

    // Filters (uniform scalar loads -> SGPRs).
    float w[8], sc[8];
#pragma unroll
    for (int j = 0; j < 8; ++j) {
        w[j]  = scaling_rec[7 - j] * ((j & 1) ? -1.0f : 1.0f);
        sc[j] = scaling[j];
    }

    // Dense payload: lane l <-> float4 tl. One instruction = contiguous 1 KB.
    // v = (E[k0], O[k0], E[k0+1], O[k0+1]), k0 = 2*tl.
    const float4 v = ((const float4*)in_row)[tl];

    // Predecessor float4s t-1..t-4 via shfl_up (garbage on lanes < d).
    float u1x = __shfl_up(v.x, 1), u1y = __shfl_up(v.y, 1);
    float u1z = __shfl_up(v.z, 1), u1w = __shfl_up(v.w, 1);
    float u2x = __shfl_up(v.x, 2), u2y = __shfl_up(v.y, 2);
    float u2z = __shfl_up(v.z, 2), u2w = __shfl_up(v.w, 2);
    float u3x = __shfl_up(v.x, 3), u3y = __shfl_up(v.y, 3);
    float u3z = __shfl_up(v.z, 3), u3w = __shfl_up(v.w, 3);
    float u4z = __shfl_up(v.z, 4), u4w = __shfl_up(v.w, 4);  // only pair k0-7 needed

    // Lanes 0..3: patch the d > lane predecessors with direct loads
    // (circular wrap within the row; all 4 float4s share one 64-B line
    // except at the row-start wrap, where they come from the row tail).
    if (lane < 1) { const float4 h = ((const float4*)in_row)[(tl - 1) & (F4_PER_ROW - 1)];
                    u1x = h.x; u1y = h.y; u1z = h.z; u1w = h.w; }
    if (lane < 2) { const float4 h = ((const float4*)in_row)[(tl - 2) & (F4_PER_ROW - 1)];
                    u2x = h.x; u2y = h.y; u2z = h.z; u2w = h.w; }
    if (lane < 3) { const float4 h = ((const float4*)in_row)[(tl - 3) & (F4_PER_ROW - 1)];
                    u3x = h.x; u3y = h.y; u3z = h.z; u3w = h.w; }
    if (lane < 4) { const float4 h = ((const float4*)in_row)[(tl - 4) & (F4_PER_ROW - 1)];
                    u4z = h.z; u4w = h.w; }

    // Window: pair (k0-7+i) -> pe[i]/po[i], i = 0..8.
    float pe[9], po[9];
    pe[0] = u4z; po[0] = u4w;
    pe[1] = u3x; po[1] = u3y;  pe[2] = u3z; po[2] = u3w;
    pe[3] = u2x; po[3] = u2y;  pe[4] = u2z; po[4] = u2w;
    pe[5] = u1x; po[5] = u1y;  pe[6] = u1z; po[6] = u1w;
    pe[7] = v.x; po[7] = v.y;  pe[8] = v.z; po[8] = v.w;

    // even_out[k0+q] = pe[7+q] - sum_j po[7+q-j]*sc[j]   (q = 0,1)
    // odd_out [k0+q] = po[7+q] - sum_j pe[7+q-j]*w[j]
    float eo0 = pe[7], oo0 = po[7], eo1 = pe[8], oo1 = po[8];
#pragma unroll
    for (int j = 0; j < 8; ++j) {
        eo0 -= po[7 - j] * sc[j];
        oo0 -= pe[7 - j] * w[j];
        eo1 -= po[8 - j] * sc[j];
        oo1 -= pe[8 - j] * w[j];
    }

    // Dense stores: lane l writes 8 B at offset 8*l -> one instruction
    // covers a contiguous 512 B per wave (global_store_dwordx2).
    float* oe = out + (size_t)row * HALF + 2 * tl;
    float* od = out + (size_t)rows * HALF + (size_t)row * HALF + 2 * tl;
    ((float2*)oe)[0] = make_float2(eo0, eo1);
    ((float2*)od)[0] = make_float2(oo0, oo1);
}

extern "C" void kernel_launch(void* const* d_in, const int* in_sizes, int n_in,
                              void* d_out, int out_size, void* d_ws, size_t ws_size,
                              hipStream_t stream) {
    const float* input       = (const float*)d_in[0];
    const float* scaling     = (const float*)d_in[1];
    const float* scaling_rec = (const float*)d_in[2];
    float*       out         = (float*)d_out;

    const int rows    = in_sizes[0] / COLS;                 // 4096
    const int threads = rows * F4_PER_ROW;                  // 8,388,608
    fwd_dwt_kernel<<<threads / NTHREADS, NTHREADS, 0, stream>>>(
        input, scaling, scaling_rec, out, rows);
}

// Round 5
// 228.748 us; speedup vs baseline: 1.0688x; 1.0429x over previous
//
#include <hip/hip_runtime.h>

// ForwardTransformLayer: lifting step with circular 8-tap convolutions.
//   even = in[:, ::2], odd = in[:, 1::2]            (row length 8192 -> 4096 each)
//   odd_out[k]  = odd[k]  - sum_j even[(k-j) mod n] * wavelet[j]
//   even_out[k] = even[k] - sum_j odd[(k-j)  mod n] * scaling[j]
//   wavelet[j] = scaling_rec[7-j] * (j odd ? -1 : +1)
// d_out layout: even_out (rows*4096) then odd_out (rows*4096), row-major.
//
// R8 design: falsified so far -- traffic volume (R2), halo scheme (R3),
// occupancy/pipelining (R4), store cache policy (R6), per-instruction
// density (R7). All pinned at 80-89 us with no saturated queue (VALU 22%,
// wire 31%, LDS ~20%, L1 ~8%). Remaining shared structure: the dependency
// chain  global load -> 14 dependent ds_permute (shfl) -> FMA -> store.
// Fix: delete the cross-lane chain. Pairs k0-7..k0-1 are float4s f-4..f-1,
// i.e. the wave's own contiguous window shifted by 16k bytes. Load them as
// 4 extra DENSE float4 loads (each a contiguous 1-KB wave window, ~94%
// L1-hits of the payload window). No shfl, no divergent patch, no DS pipe;
// 5 mutually independent loads per wave (MLP 1 -> 5); only chain left is
// load -> FMA -> store.

#define COLS       8192
#define HALF       4096                       // pairs per row
#define F4_PER_ROW 2048                       // float4s per row (2 pairs each)
#define NTHREADS   256

__global__ __launch_bounds__(NTHREADS) void fwd_dwt_kernel(
    const float* __restrict__ input,
    const float* __restrict__ scaling,
    const float* __restrict__ scaling_rec,
    float* __restrict__ out,
    int rows)
{
    const int t   = blockIdx.x * NTHREADS + threadIdx.x;   // global float4 index
    const int row = t >> 11;                               // / F4_PER_ROW
    const int f   = t & (F4_PER_ROW - 1);                  // row-local float4 idx

    const float4* in4 = (const float4*)(input + (size_t)row * COLS);

    // Filters (uniform scalar loads -> SGPRs).
    float w[8], sc[8];
#pragma unroll
    for (int j = 0; j < 8; ++j) {
        w[j]  = scaling_rec[7 - j] * ((j & 1) ? -1.0f : 1.0f);
        sc[j] = scaling[j];
    }

    // Five dense, mutually independent loads. v covers pairs (k0, k0+1),
    // h1..h4 cover pairs k0-2..k0-1, k0-4..k0-3, k0-6..k0-5, k0-8..k0-7.
    // Circular wrap within the row via & (F4_PER_ROW-1).
    const float4 v  = in4[f];
    const float4 h1 = in4[(f - 1) & (F4_PER_ROW - 1)];
    const float4 h2 = in4[(f - 2) & (F4_PER_ROW - 1)];
    const float4 h3 = in4[(f - 3) & (F4_PER_ROW - 1)];
    const float4 h4 = in4[(f - 4) & (F4_PER_ROW - 1)];

    // Window: pair (k0-7+i) -> pe[i]/po[i], i = 0..8.  k0 = 2*f.
    float pe[9], po[9];
    pe[0] = h4.z; po[0] = h4.w;
    pe[1] = h3.x; po[1] = h3.y;  pe[2] = h3.z; po[2] = h3.w;
    pe[3] = h2.x; po[3] = h2.y;  pe[4] = h2.z; po[4] = h2.w;
    pe[5] = h1.x; po[5] = h1.y;  pe[6] = h1.z; po[6] = h1.w;
    pe[7] = v.x;  po[7] = v.y;   pe[8] = v.z;  po[8] = v.w;

    // even_out[k0+q] = pe[7+q] - sum_j po[7+q-j]*sc[j]   (q = 0,1)
    // odd_out [k0+q] = po[7+q] - sum_j pe[7+q-j]*w[j]
    float eo0 = pe[7], oo0 = po[7], eo1 = pe[8], oo1 = po[8];
#pragma unroll
    for (int j = 0; j < 8; ++j) {
        eo0 -= po[7 - j] * sc[j];
        oo0 -= pe[7 - j] * w[j];
        eo1 -= po[8 - j] * sc[j];
        oo1 -= pe[8 - j] * w[j];
    }

    // Dense stores: lane l writes 8 B at offset 8*l -> one instruction
    // covers a contiguous 512 B per wave (global_store_dwordx2).
    float* oe = out + (size_t)row * HALF + 2 * f;
    float* od = out + (size_t)rows * HALF + (size_t)row * HALF + 2 * f;
    ((float2*)oe)[0] = make_float2(eo0, eo1);
    ((float2*)od)[0] = make_float2(oo0, oo1);
}

extern "C" void kernel_launch(void* const* d_in, const int* in_sizes, int n_in,
                              void* d_out, int out_size, void* d_ws, size_t ws_size,
                              hipStream_t stream) {
    const float* input       = (const float*)d_in[0];
    const float* scaling     = (const float*)d_in[1];
    const float* scaling_rec = (const float*)d_in[2];
    float*       out         = (float*)d_out;

    const int rows    = in_sizes[0] / COLS;                 // 4096
    const int threads = rows * F4_PER_ROW;                  // 8,388,608
    fwd_dwt_kernel<<<threads / NTHREADS, NTHREADS, 0, stream>>>(
        input, scaling, scaling_rec, out, rows);
}